// Round 24
// baseline (190.435 us; speedup 1.0000x reference)
//
#include <hip/hip_runtime.h>

typedef __bf16 bf16_t;
typedef __bf16 bf16x4 __attribute__((ext_vector_type(4)));
typedef __bf16 bf16x8 __attribute__((ext_vector_type(8)));
typedef float f32x4 __attribute__((ext_vector_type(4)));
typedef float f32x4v __attribute__((ext_vector_type(4)));

#define GLOAD_LDS16(gptr, lptr) \
  __builtin_amdgcn_global_load_lds((const __attribute__((address_space(1))) void*)(gptr), \
                                   (__attribute__((address_space(3))) void*)(lptr), 16, 0, 0)

// ---------------------------------------------------------------- casts -----

__global__ __launch_bounds__(256) void cast_x_kernel(
    const float* __restrict__ q, const float* __restrict__ k,
    const float* __restrict__ v, bf16_t* __restrict__ out) {
  const int z = blockIdx.y;
  const float* src = (z == 0) ? q : (z == 1) ? k : v;
  size_t i = ((size_t)blockIdx.x * 256 + threadIdx.x) * 4;
  f32x4v val = *(const f32x4v*)(src + i);
  bf16x4 o;
  o[0] = (bf16_t)val[0]; o[1] = (bf16_t)val[1];
  o[2] = (bf16_t)val[2]; o[3] = (bf16_t)val[3];
  *(bf16x4*)(out + (size_t)z * 8388608 + i) = o;
}

// W[k][n] f32 -> Wt[n][k] bf16 (B^T layout). z=0 (Wq) folds scale*log2(e).
__global__ __launch_bounds__(256) void cast_w_kernel(
    const float* __restrict__ W0, const float* __restrict__ W1,
    const float* __restrict__ W2, const float* __restrict__ W3,
    bf16_t* __restrict__ Wt) {
  const int z = blockIdx.z;
  const float* W = (z == 0) ? W0 : (z == 1) ? W1 : (z == 2) ? W2 : W3;
  const float sc = (z == 0) ? 0.18033688011112042f : 1.0f;  // 64^-0.5 * log2(e)
  __shared__ float tile[64][65];
  const int n0 = blockIdx.x * 64, k0 = blockIdx.y * 64;
  const int t = threadIdx.x;
  const int r = t >> 4, c4 = (t & 15) * 4;
#pragma unroll
  for (int p = 0; p < 4; p++) {
    f32x4v v = *(const f32x4v*)&W[(size_t)(k0 + r + p * 16) * 1024 + n0 + c4];
    tile[r + p * 16][c4 + 0] = v[0]; tile[r + p * 16][c4 + 1] = v[1];
    tile[r + p * 16][c4 + 2] = v[2]; tile[r + p * 16][c4 + 3] = v[3];
  }
  __syncthreads();
  const int r2 = t >> 3, c2 = (t & 7) * 8;
  bf16_t* dst = Wt + (size_t)z * 1048576;
#pragma unroll
  for (int p = 0; p < 2; p++) {
    bf16x8 o;
#pragma unroll
    for (int i = 0; i < 8; i++) o[i] = (bf16_t)(tile[c2 + i][r2 + p * 32] * sc);
    *(bf16x8*)&dst[(size_t)(n0 + r2 + p * 32) * 1024 + k0 + c2] = o;
  }
}

// ---------------------------------------------------------------- GEMM ------
// (unchanged m97-structure 128x128 GEMM, mt-fastest grid)
template <int EPI>
__global__ __launch_bounds__(256) void gemm_bt(
    const bf16_t* __restrict__ Abase, const bf16_t* __restrict__ Wtbase,
    void* __restrict__ outp) {
  __shared__ bf16_t As[128 * 32];
  __shared__ bf16_t Bs[128 * 32];
  const int mt = blockIdx.x, nt = blockIdx.y, z = blockIdx.z;
  const int tid = threadIdx.x, wave = tid >> 6, lane = tid & 63;
  const bf16_t* A = Abase + (size_t)z * 8388608 + (size_t)mt * 128 * 1024;
  const bf16_t* Bt = Wtbase + (size_t)z * 1048576 + (size_t)nt * 128 * 1024;

  const int wm = wave >> 1, wn = wave & 1;
  const int frow = lane & 15, fk = (lane >> 4) * 8;
  const int srow = lane >> 2, scol = (lane & 3) * 8;

  f32x4 acc[4][4];
#pragma unroll
  for (int i = 0; i < 4; i++)
#pragma unroll
    for (int j = 0; j < 4; j++) acc[i][j] = (f32x4){0.f, 0.f, 0.f, 0.f};

  for (int k0 = 0; k0 < 1024; k0 += 32) {
#pragma unroll
    for (int r = 0; r < 2; r++) {
      const int c = wave * 2 + r;
      GLOAD_LDS16(A + (size_t)(c * 16 + srow) * 1024 + k0 + scol, &As[c * 512]);
      GLOAD_LDS16(Bt + (size_t)(c * 16 + srow) * 1024 + k0 + scol, &Bs[c * 512]);
    }
    __syncthreads();
    bf16x8 af[4], bfr[4];
#pragma unroll
    for (int i = 0; i < 4; i++)
      af[i] = *(const bf16x8*)&As[(wm * 64 + i * 16 + frow) * 32 + fk];
#pragma unroll
    for (int j = 0; j < 4; j++)
      bfr[j] = *(const bf16x8*)&Bs[(wn * 64 + j * 16 + frow) * 32 + fk];
#pragma unroll
    for (int i = 0; i < 4; i++)
#pragma unroll
      for (int j = 0; j < 4; j++)
        acc[i][j] = __builtin_amdgcn_mfma_f32_16x16x32_bf16(af[i], bfr[j],
                                                            acc[i][j], 0, 0, 0);
    __syncthreads();
  }

  const int rbase = mt * 128 + wm * 64;
  if constexpr (EPI == 0) {
    bf16_t* out = (bf16_t*)outp + (size_t)z * 8388608;
    const int h = nt * 2 + wn;
#pragma unroll
    for (int i = 0; i < 4; i++)
#pragma unroll
      for (int j = 0; j < 4; j++)
#pragma unroll
        for (int r = 0; r < 4; r++) {
          int row_g = rbase + i * 16 + (lane >> 4) * 4 + r;
          int b = row_g >> 11, s = row_g & 2047;
          int dd = j * 16 + frow;
          out[(((size_t)(b * 16 + h)) * 2048 + s) * 64 + dd] = (bf16_t)acc[i][j][r];
        }
  } else {
    float* out = (float*)outp;
#pragma unroll
    for (int i = 0; i < 4; i++)
#pragma unroll
      for (int j = 0; j < 4; j++)
#pragma unroll
        for (int r = 0; r < 4; r++) {
          int row_g = rbase + i * 16 + (lane >> 4) * 4 + r;
          int col_g = nt * 128 + wn * 64 + j * 16 + frow;
          out[(size_t)row_g * 1024 + col_g] = acc[i][j][r];
        }
  }
}

// ------------------------------------------------------------- attention ----
// Swapped-QK^T causal flash. R18 tile body VERBATIM (8 waves x 16 q-rows,
// KVBLK=64, K in LDS pad 72, fragment-ordered swizzled VT) but ONE 128-row
// strip per block: grid 64x16 = 1024 blocks = exactly 4/CU = 32 waves/CU
// (the HW cap; R18's pair-loop gave only 2 blocks/CU). Balanced y->qt remap:
// every {y,y+4,y+8,y+12} residency set sums to 30 work-units.
__global__ __launch_bounds__(512) void attn_fwd(const bf16_t* __restrict__ qkv,
                                                bf16_t* __restrict__ ctx) {
  const int bh = blockIdx.x;
  const int y = blockIdx.y;
  // balanced remap: hi=y>>2 selects ramp; sets {y,y+4,y+8,y+12} sum to 30
  const int yq = y & 3, hi = y >> 2;
  const int qt = (hi == 0) ? 15 - 2 * yq
               : (hi == 1) ? 2 * yq
               : (hi == 2) ? 14 - 2 * yq
                           : 1 + 2 * yq;
  const int b = bh >> 4, h = bh & 15;
  const size_t HS = (size_t)2048 * 64;
  const bf16_t* Qp = qkv + (size_t)bh * HS;
  const bf16_t* Kp = qkv + 8388608 + (size_t)bh * HS;
  const bf16_t* Vp = qkv + 16777216 + (size_t)bh * HS;

  __shared__ bf16_t Klds[64 * 72];  // K row-major [kv][d], pad 72
  __shared__ bf16_t VT[64 * 72];    // V^T fragment-ordered [d][slot^swz]

  const int tid = threadIdx.x, wave = tid >> 6, lane = tid & 63;
  const int q15 = lane & 15, g = lane >> 4;
  const int ldrow = tid >> 3, ldcol = (tid & 7) * 8;  // K staging (64x64 once)
  // V staging: this lane owns row kv0+lane, cols wave*8 .. wave*8+7
  const int vslot = ((lane >> 5) << 5) | (((lane >> 2) & 3) << 3) |
                    (((lane >> 4) & 1) << 2) | (lane & 3);

  const int qbase = qt * 128 + wave * 16;  // wave's 16 q-rows
  const int nkv = qt * 2 + 2;
  const int qmax = qbase + 15;

  // Q fragments direct from global (16 rows x 64B segments)
  bf16x8 qf[2];
#pragma unroll
  for (int kf = 0; kf < 2; kf++)
    qf[kf] = *(const bf16x8*)&Qp[(size_t)(qbase + q15) * 64 + kf * 32 + g * 8];

  float m = -1e30f, l = 0.f;
  f32x4 of[4];
#pragma unroll
  for (int nd = 0; nd < 4; nd++) of[nd] = (f32x4){0.f, 0.f, 0.f, 0.f};

  for (int kv = 0; kv < nkv; ++kv) {
    const int kv0 = kv * 64;
    bf16x8 kreg = *(const bf16x8*)&Kp[(size_t)(kv0 + ldrow) * 64 + ldcol];
    bf16x8 vreg = *(const bf16x8*)&Vp[(size_t)(kv0 + lane) * 64 + wave * 8];
    __syncthreads();  // all waves done reading LDS of previous tile
    *(bf16x8*)&Klds[ldrow * 72 + ldcol] = kreg;
#pragma unroll
    for (int i = 0; i < 8; i++) {
      const int d = wave * 8 + i;
      VT[d * 72 + (vslot ^ (d & 56))] = vreg[i];
    }
    __syncthreads();

    if (kv0 > qmax) continue;  // tile fully above diagonal for this wave

    // ---- S^T = K . Q^T : sf[nf], lane: q = q15, kv = nf*16 + g*4 + r
    f32x4 sf[4];
#pragma unroll
    for (int nf = 0; nf < 4; nf++) {
      bf16x8 ka = *(const bf16x8*)&Klds[(nf * 16 + q15) * 72 + g * 8];
      bf16x8 kb = *(const bf16x8*)&Klds[(nf * 16 + q15) * 72 + 32 + g * 8];
      f32x4 a = (f32x4){0.f, 0.f, 0.f, 0.f};
      a = __builtin_amdgcn_mfma_f32_16x16x32_bf16(ka, qf[0], a, 0, 0, 0);
      a = __builtin_amdgcn_mfma_f32_16x16x32_bf16(kb, qf[1], a, 0, 0, 0);
      sf[nf] = a;
    }

    if (kv0 + 63 > qbase) {  // the wave's single diagonal tile
      int q_g = qbase + q15;
#pragma unroll
      for (int nf = 0; nf < 4; nf++)
#pragma unroll
        for (int r = 0; r < 4; r++)
          if (kv0 + nf * 16 + g * 4 + r > q_g) sf[nf][r] = -1e30f;
    }

    // ---- online softmax, in-lane (16 vals) + 2 shfl across g-groups
    float pmax = sf[0][0];
#pragma unroll
    for (int nf = 0; nf < 4; nf++)
#pragma unroll
      for (int r = 0; r < 4; r++) pmax = fmaxf(pmax, sf[nf][r]);
    pmax = fmaxf(pmax, __shfl_xor(pmax, 16));
    pmax = fmaxf(pmax, __shfl_xor(pmax, 32));
    float mold = m;
    if (!__all(pmax <= mold + 8.0f)) {  // defer-max
      float mnew = fmaxf(mold, pmax);
      float alpha = __builtin_amdgcn_exp2f(mold - mnew);
      m = mnew;
      l *= alpha;
#pragma unroll
      for (int r = 0; r < 4; r++) {
        float aO = __shfl(alpha, (lane & 48) | (g * 4 + r));
#pragma unroll
        for (int nd = 0; nd < 4; nd++) of[nd][r] *= aO;
      }
    }
    float mm = m;
    float rs = 0.f;
#pragma unroll
    for (int nf = 0; nf < 4; nf++)
#pragma unroll
      for (int r = 0; r < 4; r++) {
        float pp = __builtin_amdgcn_exp2f(sf[nf][r] - mm);
        sf[nf][r] = pp;
        rs += pp;
      }
    rs += __shfl_xor(rs, 16);
    rs += __shfl_xor(rs, 32);
    l += rs;
    // pack P: ap[kf][j] = P[q][kf*32+(j>>2)*16+g*4+(j&3)]
    bf16x8 ap[2];
#pragma unroll
    for (int kf = 0; kf < 2; kf++)
#pragma unroll
      for (int j2 = 0; j2 < 4; j2++) {
        ap[kf][j2] = (bf16_t)sf[2 * kf][j2];
        ap[kf][j2 + 4] = (bf16_t)sf[2 * kf + 1][j2];
      }

    // ---- O += P V ; B-fragment = single b128 from fragment-ordered VT
#pragma unroll
    for (int nd = 0; nd < 4; nd++) {
      const int d = nd * 16 + q15;
      const int swz = d & 56;
      bf16x8 vv0 = *(const bf16x8*)&VT[d * 72 + ((g * 8) ^ swz)];
      bf16x8 vv1 = *(const bf16x8*)&VT[d * 72 + ((32 + g * 8) ^ swz)];
      of[nd] = __builtin_amdgcn_mfma_f32_16x16x32_bf16(ap[0], vv0,
                                                       of[nd], 0, 0, 0);
      of[nd] = __builtin_amdgcn_mfma_f32_16x16x32_bf16(ap[1], vv1,
                                                       of[nd], 0, 0, 0);
    }
  }

  // ---- epilogue: O /= l (l lives at q=lane&15 layout -> shfl to O layout)
  float rcpO[4];
#pragma unroll
  for (int r = 0; r < 4; r++) {
    float lO = __shfl(l, (lane & 48) | (g * 4 + r));
    rcpO[r] = 1.0f / lO;
  }
#pragma unroll
  for (int nd = 0; nd < 4; nd++)
#pragma unroll
    for (int r = 0; r < 4; r++) {
      int srow_ = qbase + g * 4 + r;
      ctx[((size_t)(b * 2048 + srow_)) * 1024 + h * 64 + nd * 16 + q15] =
          (bf16_t)(of[nd][r] * rcpO[r]);
    }
}

// ---------------------------------------------------------------- launch ----

extern "C" void kernel_launch(void* const* d_in, const int* in_sizes, int n_in,
                              void* d_out, int out_size, void* d_ws, size_t ws_size,
                              hipStream_t stream) {
  const float* queries = (const float*)d_in[0];
  const float* keys    = (const float*)d_in[1];
  const float* values  = (const float*)d_in[2];
  const float* Wq = (const float*)d_in[4];
  const float* Wk = (const float*)d_in[5];
  const float* Wv = (const float*)d_in[6];
  const float* Wo = (const float*)d_in[7];

  char* ws = (char*)d_ws;
  bf16_t* Xb  = (bf16_t*)ws;                    // [3][8192][1024] bf16 (48MB)
  bf16_t* qkv = (bf16_t*)(ws + 50331648);       // [3][B,H,S,64]  bf16 (48MB)
  bf16_t* Wt  = (bf16_t*)(ws + 100663296);      // [4][1024][1024] bf16 (8MB)
  bf16_t* ctx = Xb;                             // reuse X region after QKV GEMM
  float* out = (float*)d_out;

  cast_x_kernel<<<dim3(8192, 3), 256, 0, stream>>>(queries, keys, values, Xb);
  cast_w_kernel<<<dim3(16, 16, 4), 256, 0, stream>>>(Wq, Wk, Wv, Wo, Wt);
  gemm_bt<0><<<dim3(64, 8, 3), 256, 0, stream>>>(Xb, Wt, (void*)qkv);
  attn_fwd<<<dim3(64, 16), 512, 0, stream>>>(qkv, ctx);
  gemm_bt<1><<<dim3(64, 8, 1), 256, 0, stream>>>(ctx, Wt + 3 * 1048576, (void*)out);
}

// Round 25
// 182.625 us; speedup vs baseline: 1.0428x; 1.0428x over previous
//
#include <hip/hip_runtime.h>

typedef __bf16 bf16_t;
typedef __bf16 bf16x4 __attribute__((ext_vector_type(4)));
typedef __bf16 bf16x8 __attribute__((ext_vector_type(8)));
typedef float f32x4 __attribute__((ext_vector_type(4)));
typedef float f32x4v __attribute__((ext_vector_type(4)));

#define GLOAD_LDS16(gptr, lptr) \
  __builtin_amdgcn_global_load_lds((const __attribute__((address_space(1))) void*)(gptr), \
                                   (__attribute__((address_space(3))) void*)(lptr), 16, 0, 0)

// ---------------------------------------------------------------- casts -----
// Fused: z=0..2 cast X slabs (q,k,v f32->bf16); z=3 cast+transpose W (only
// first 1024 x-blocks active). Saves one serialized kernel launch.
__global__ __launch_bounds__(256) void cast_all_kernel(
    const float* __restrict__ q, const float* __restrict__ k,
    const float* __restrict__ v, bf16_t* __restrict__ out,
    const float* __restrict__ W0, const float* __restrict__ W1,
    const float* __restrict__ W2, const float* __restrict__ W3,
    bf16_t* __restrict__ Wt) {
  const int z = blockIdx.y;
  if (z < 3) {
    const float* src = (z == 0) ? q : (z == 1) ? k : v;
    size_t i = ((size_t)blockIdx.x * 256 + threadIdx.x) * 4;
    f32x4v val = *(const f32x4v*)(src + i);
    bf16x4 o;
    o[0] = (bf16_t)val[0]; o[1] = (bf16_t)val[1];
    o[2] = (bf16_t)val[2]; o[3] = (bf16_t)val[3];
    *(bf16x4*)(out + (size_t)z * 8388608 + i) = o;
    return;
  }
  // W path: x in [0,1024): wz = x>>8 selects matrix, tile = x&255
  const int x = blockIdx.x;
  if (x >= 1024) return;
  const int wz = x >> 8, tile_id = x & 255;
  const float* W = (wz == 0) ? W0 : (wz == 1) ? W1 : (wz == 2) ? W2 : W3;
  const float sc = (wz == 0) ? 0.18033688011112042f : 1.0f;  // 64^-0.5*log2e
  __shared__ float tile[64][65];
  const int n0 = (tile_id & 15) * 64, k0 = (tile_id >> 4) * 64;
  const int t = threadIdx.x;
  const int r = t >> 4, c4 = (t & 15) * 4;
#pragma unroll
  for (int p = 0; p < 4; p++) {
    f32x4v vv = *(const f32x4v*)&W[(size_t)(k0 + r + p * 16) * 1024 + n0 + c4];
    tile[r + p * 16][c4 + 0] = vv[0]; tile[r + p * 16][c4 + 1] = vv[1];
    tile[r + p * 16][c4 + 2] = vv[2]; tile[r + p * 16][c4 + 3] = vv[3];
  }
  __syncthreads();
  const int r2 = t >> 3, c2 = (t & 7) * 8;
  bf16_t* dst = Wt + (size_t)wz * 1048576;
#pragma unroll
  for (int p = 0; p < 2; p++) {
    bf16x8 o;
#pragma unroll
    for (int i = 0; i < 8; i++) o[i] = (bf16_t)(tile[c2 + i][r2 + p * 32] * sc);
    *(bf16x8*)&dst[(size_t)(n0 + r2 + p * 32) * 1024 + k0 + c2] = o;
  }
}

// ---------------------------------------------------------------- GEMM ------
// (unchanged m97-structure 128x128 GEMM, mt-fastest grid)
template <int EPI>
__global__ __launch_bounds__(256) void gemm_bt(
    const bf16_t* __restrict__ Abase, const bf16_t* __restrict__ Wtbase,
    void* __restrict__ outp) {
  __shared__ bf16_t As[128 * 32];
  __shared__ bf16_t Bs[128 * 32];
  const int mt = blockIdx.x, nt = blockIdx.y, z = blockIdx.z;
  const int tid = threadIdx.x, wave = tid >> 6, lane = tid & 63;
  const bf16_t* A = Abase + (size_t)z * 8388608 + (size_t)mt * 128 * 1024;
  const bf16_t* Bt = Wtbase + (size_t)z * 1048576 + (size_t)nt * 128 * 1024;

  const int wm = wave >> 1, wn = wave & 1;
  const int frow = lane & 15, fk = (lane >> 4) * 8;
  const int srow = lane >> 2, scol = (lane & 3) * 8;

  f32x4 acc[4][4];
#pragma unroll
  for (int i = 0; i < 4; i++)
#pragma unroll
    for (int j = 0; j < 4; j++) acc[i][j] = (f32x4){0.f, 0.f, 0.f, 0.f};

  for (int k0 = 0; k0 < 1024; k0 += 32) {
#pragma unroll
    for (int r = 0; r < 2; r++) {
      const int c = wave * 2 + r;
      GLOAD_LDS16(A + (size_t)(c * 16 + srow) * 1024 + k0 + scol, &As[c * 512]);
      GLOAD_LDS16(Bt + (size_t)(c * 16 + srow) * 1024 + k0 + scol, &Bs[c * 512]);
    }
    __syncthreads();
    bf16x8 af[4], bfr[4];
#pragma unroll
    for (int i = 0; i < 4; i++)
      af[i] = *(const bf16x8*)&As[(wm * 64 + i * 16 + frow) * 32 + fk];
#pragma unroll
    for (int j = 0; j < 4; j++)
      bfr[j] = *(const bf16x8*)&Bs[(wn * 64 + j * 16 + frow) * 32 + fk];
#pragma unroll
    for (int i = 0; i < 4; i++)
#pragma unroll
      for (int j = 0; j < 4; j++)
        acc[i][j] = __builtin_amdgcn_mfma_f32_16x16x32_bf16(af[i], bfr[j],
                                                            acc[i][j], 0, 0, 0);
    __syncthreads();
  }

  const int rbase = mt * 128 + wm * 64;
  if constexpr (EPI == 0) {
    bf16_t* out = (bf16_t*)outp + (size_t)z * 8388608;
    const int h = nt * 2 + wn;
#pragma unroll
    for (int i = 0; i < 4; i++)
#pragma unroll
      for (int j = 0; j < 4; j++)
#pragma unroll
        for (int r = 0; r < 4; r++) {
          int row_g = rbase + i * 16 + (lane >> 4) * 4 + r;
          int b = row_g >> 11, s = row_g & 2047;
          int dd = j * 16 + frow;
          out[(((size_t)(b * 16 + h)) * 2048 + s) * 64 + dd] = (bf16_t)acc[i][j][r];
        }
  } else {
    float* out = (float*)outp;
#pragma unroll
    for (int i = 0; i < 4; i++)
#pragma unroll
      for (int j = 0; j < 4; j++)
#pragma unroll
        for (int r = 0; r < 4; r++) {
          int row_g = rbase + i * 16 + (lane >> 4) * 4 + r;
          int col_g = nt * 128 + wn * 64 + j * 16 + frow;
          out[(size_t)row_g * 1024 + col_g] = acc[i][j][r];
        }
  }
}

// ------------------------------------------------------------- attention ----
// EXACT R18 structure (best measured: 72.1 us) + T5 s_setprio around the
// two MFMA clusters (clean A/B; never isolated on this base before).
__global__ __launch_bounds__(512) void attn_fwd(const bf16_t* __restrict__ qkv,
                                                bf16_t* __restrict__ ctx) {
  const int bh = blockIdx.x;
  const int y = blockIdx.y;  // strip pair (y, 15-y)
  const int b = bh >> 4, h = bh & 15;
  const size_t HS = (size_t)2048 * 64;
  const bf16_t* Qp = qkv + (size_t)bh * HS;
  const bf16_t* Kp = qkv + 8388608 + (size_t)bh * HS;
  const bf16_t* Vp = qkv + 16777216 + (size_t)bh * HS;

  __shared__ bf16_t Klds[64 * 72];  // K row-major [kv][d], pad 72
  __shared__ bf16_t VT[64 * 72];    // V^T fragment-ordered [d][slot^swz]

  const int tid = threadIdx.x, wave = tid >> 6, lane = tid & 63;
  const int q15 = lane & 15, g = lane >> 4;
  const int ldrow = tid >> 3, ldcol = (tid & 7) * 8;  // K staging (64x64 once)
  // V staging: this lane owns row kv0+lane, cols wave*8 .. wave*8+7
  const int vslot = ((lane >> 5) << 5) | (((lane >> 2) & 3) << 3) |
                    (((lane >> 4) & 1) << 2) | (lane & 3);

#pragma unroll 1
  for (int s = 0; s < 2; s++) {
    const int qt = s ? (15 - y) : y;     // 128-row strip index
    const int qbase = qt * 128 + wave * 16;  // wave's 16 q-rows
    const int nkv = qt * 2 + 2;
    const int qmax = qbase + 15;

    // Q fragments direct from global (16 rows x 64B segments)
    bf16x8 qf[2];
#pragma unroll
    for (int kf = 0; kf < 2; kf++)
      qf[kf] = *(const bf16x8*)&Qp[(size_t)(qbase + q15) * 64 + kf * 32 + g * 8];

    float m = -1e30f, l = 0.f;
    f32x4 of[4];
#pragma unroll
    for (int nd = 0; nd < 4; nd++) of[nd] = (f32x4){0.f, 0.f, 0.f, 0.f};

    for (int kv = 0; kv < nkv; ++kv) {
      const int kv0 = kv * 64;
      bf16x8 kreg = *(const bf16x8*)&Kp[(size_t)(kv0 + ldrow) * 64 + ldcol];
      bf16x8 vreg = *(const bf16x8*)&Vp[(size_t)(kv0 + lane) * 64 + wave * 8];
      __syncthreads();  // all waves done reading LDS of previous tile
      *(bf16x8*)&Klds[ldrow * 72 + ldcol] = kreg;
#pragma unroll
      for (int i = 0; i < 8; i++) {
        const int d = wave * 8 + i;
        VT[d * 72 + (vslot ^ (d & 56))] = vreg[i];
      }
      __syncthreads();

      if (kv0 > qmax) continue;  // tile fully above diagonal for this wave

      // ---- S^T = K . Q^T : sf[nf], lane: q = q15, kv = nf*16 + g*4 + r
      f32x4 sf[4];
      __builtin_amdgcn_s_setprio(1);
#pragma unroll
      for (int nf = 0; nf < 4; nf++) {
        bf16x8 ka = *(const bf16x8*)&Klds[(nf * 16 + q15) * 72 + g * 8];
        bf16x8 kb = *(const bf16x8*)&Klds[(nf * 16 + q15) * 72 + 32 + g * 8];
        f32x4 a = (f32x4){0.f, 0.f, 0.f, 0.f};
        a = __builtin_amdgcn_mfma_f32_16x16x32_bf16(ka, qf[0], a, 0, 0, 0);
        a = __builtin_amdgcn_mfma_f32_16x16x32_bf16(kb, qf[1], a, 0, 0, 0);
        sf[nf] = a;
      }
      __builtin_amdgcn_s_setprio(0);

      if (kv0 + 63 > qbase) {  // the wave's single diagonal tile
        int q_g = qbase + q15;
#pragma unroll
        for (int nf = 0; nf < 4; nf++)
#pragma unroll
          for (int r = 0; r < 4; r++)
            if (kv0 + nf * 16 + g * 4 + r > q_g) sf[nf][r] = -1e30f;
      }

      // ---- online softmax, in-lane (16 vals) + 2 shfl across g-groups
      float pmax = sf[0][0];
#pragma unroll
      for (int nf = 0; nf < 4; nf++)
#pragma unroll
        for (int r = 0; r < 4; r++) pmax = fmaxf(pmax, sf[nf][r]);
      pmax = fmaxf(pmax, __shfl_xor(pmax, 16));
      pmax = fmaxf(pmax, __shfl_xor(pmax, 32));
      float mold = m;
      if (!__all(pmax <= mold + 8.0f)) {  // defer-max
        float mnew = fmaxf(mold, pmax);
        float alpha = __builtin_amdgcn_exp2f(mold - mnew);
        m = mnew;
        l *= alpha;
#pragma unroll
        for (int r = 0; r < 4; r++) {
          float aO = __shfl(alpha, (lane & 48) | (g * 4 + r));
#pragma unroll
          for (int nd = 0; nd < 4; nd++) of[nd][r] *= aO;
        }
      }
      float mm = m;
      float rs = 0.f;
#pragma unroll
      for (int nf = 0; nf < 4; nf++)
#pragma unroll
        for (int r = 0; r < 4; r++) {
          float pp = __builtin_amdgcn_exp2f(sf[nf][r] - mm);
          sf[nf][r] = pp;
          rs += pp;
        }
      rs += __shfl_xor(rs, 16);
      rs += __shfl_xor(rs, 32);
      l += rs;
      // pack P: ap[kf][j] = P[q][kf*32+(j>>2)*16+g*4+(j&3)]
      bf16x8 ap[2];
#pragma unroll
      for (int kf = 0; kf < 2; kf++)
#pragma unroll
        for (int j2 = 0; j2 < 4; j2++) {
          ap[kf][j2] = (bf16_t)sf[2 * kf][j2];
          ap[kf][j2 + 4] = (bf16_t)sf[2 * kf + 1][j2];
        }

      // ---- O += P V ; B-fragment = single b128 from fragment-ordered VT
      __builtin_amdgcn_s_setprio(1);
#pragma unroll
      for (int nd = 0; nd < 4; nd++) {
        const int d = nd * 16 + q15;
        const int swz = d & 56;
        bf16x8 vv0 = *(const bf16x8*)&VT[d * 72 + ((g * 8) ^ swz)];
        bf16x8 vv1 = *(const bf16x8*)&VT[d * 72 + ((32 + g * 8) ^ swz)];
        of[nd] = __builtin_amdgcn_mfma_f32_16x16x32_bf16(ap[0], vv0,
                                                         of[nd], 0, 0, 0);
        of[nd] = __builtin_amdgcn_mfma_f32_16x16x32_bf16(ap[1], vv1,
                                                         of[nd], 0, 0, 0);
      }
      __builtin_amdgcn_s_setprio(0);
    }

    // ---- epilogue: O /= l (l lives at q=lane&15 layout -> shfl to O layout)
    float rcpO[4];
#pragma unroll
    for (int r = 0; r < 4; r++) {
      float lO = __shfl(l, (lane & 48) | (g * 4 + r));
      rcpO[r] = 1.0f / lO;
    }
#pragma unroll
    for (int nd = 0; nd < 4; nd++)
#pragma unroll
      for (int r = 0; r < 4; r++) {
        int srow_ = qbase + g * 4 + r;
        ctx[((size_t)(b * 2048 + srow_)) * 1024 + h * 64 + nd * 16 + q15] =
            (bf16_t)(of[nd][r] * rcpO[r]);
      }
  }
}

// ---------------------------------------------------------------- launch ----

extern "C" void kernel_launch(void* const* d_in, const int* in_sizes, int n_in,
                              void* d_out, int out_size, void* d_ws, size_t ws_size,
                              hipStream_t stream) {
  const float* queries = (const float*)d_in[0];
  const float* keys    = (const float*)d_in[1];
  const float* values  = (const float*)d_in[2];
  const float* Wq = (const float*)d_in[4];
  const float* Wk = (const float*)d_in[5];
  const float* Wv = (const float*)d_in[6];
  const float* Wo = (const float*)d_in[7];

  char* ws = (char*)d_ws;
  bf16_t* Xb  = (bf16_t*)ws;                    // [3][8192][1024] bf16 (48MB)
  bf16_t* qkv = (bf16_t*)(ws + 50331648);       // [3][B,H,S,64]  bf16 (48MB)
  bf16_t* Wt  = (bf16_t*)(ws + 100663296);      // [4][1024][1024] bf16 (8MB)
  bf16_t* ctx = Xb;                             // reuse X region after QKV GEMM
  float* out = (float*)d_out;

  cast_all_kernel<<<dim3(8192, 4), 256, 0, stream>>>(queries, keys, values, Xb,
                                                     Wq, Wk, Wv, Wo, Wt);
  gemm_bt<0><<<dim3(64, 8, 3), 256, 0, stream>>>(Xb, Wt, (void*)qkv);
  attn_fwd<<<dim3(64, 8), 512, 0, stream>>>(qkv, ctx);
  gemm_bt<1><<<dim3(64, 8, 1), 256, 0, stream>>>(ctx, Wt + 3 * 1048576, (void*)out);
}